// Round 8
// baseline (66.353 us; speedup 1.0000x reference)
//
#include <hip/hip_runtime.h>

// GaussianKernel: out[row, o] = exp(-(||x_row||^2 - 2 x_row.w_o + ||w_o||^2)) + b[o]
// x: 262144 rows x 32 fp32; w: [32,128]; b: [128]; out fp32.
//
// Round-7 post-mortem: per-row fetches are COLD (x streams once) -> each row
// pays ~500-900 cyc L3/HBM latency; 2-deep pipeline covers only ~90 cyc; both
// scalar and vector per-row variants wall at ~280 cyc/row (~60 us). Fix: stage
// the block's whole 16 KB x-tile in LDS with 1024 concurrent coalesced float4
// loads (latency paid once per block), consume rows via uniform-address
// ds_read_b128 broadcast (conflict-free, ~120 cyc, compiler-pipelined).

constexpr int C_DIM  = 32;
constexpr int OUT_DIM = 128;
constexpr int ROWS_PER_WAVE  = 64;    // lane l owns xsq of rowGrp*64 + l
constexpr int ROWS_PER_BLOCK = 128;   // 2 rowGrps x 64 rows
constexpr float LOG2E = 1.4426950408889634f;

__global__ __launch_bounds__(256, 4)
void gaussian_rbf_kernel(const float* __restrict__ x,
                         const float* __restrict__ w,
                         const float* __restrict__ bias,
                         float* __restrict__ out,
                         int total_rows)
{
    __shared__ float xtile[ROWS_PER_BLOCK * C_DIM];   // 16 KB, row-major [128][32]

    const int tid  = threadIdx.x;
    const int lane = tid & 63;
    const int wid  = tid >> 6;
    const int colHalf = wid & 1;   // which 64-column half this wave owns
    const int rowGrp  = wid >> 1;  // which 64-row group this wave owns
    const int o = colHalf * 64 + lane;

    const long block_row0 = (long)blockIdx.x * ROWS_PER_BLOCK;

    // --- stage the x tile: 1024 float4 = 16 KB, 4 coalesced loads per thread.
    // All 1024 VMEM ops in flight at once: HBM latency paid once per block.
    {
        const float4* xg = reinterpret_cast<const float4*>(x + block_row0 * C_DIM);
        float4* xs = reinterpret_cast<float4*>(xtile);
#pragma unroll
        for (int i = 0; i < 4; ++i)
            xs[tid + i * 256] = xg[tid + i * 256];
    }

    // --- per-lane xsq: lane l owns ||x_{rowGrp*64+l}||^2 (reads overlap staging,
    // hit L1/L2; kept out of LDS so the epilogue has no lgkm dependency).
    float xsq_l = 0.f;
    {
        const float4* xp = reinterpret_cast<const float4*>(
            x + (block_row0 + rowGrp * ROWS_PER_WAVE + lane) * C_DIM);
#pragma unroll
        for (int k = 0; k < 8; ++k) {
            const float4 v = xp[k];
            xsq_l = fmaf(v.x, v.x, xsq_l);
            xsq_l = fmaf(v.y, v.y, xsq_l);
            xsq_l = fmaf(v.z, v.z, xsq_l);
            xsq_l = fmaf(v.w, v.w, xsq_l);
        }
    }

    // --- one w column per lane, pinned in VGPRs ---
    float wc[C_DIM];
    float wsq = 0.f;
#pragma unroll
    for (int c = 0; c < C_DIM; ++c) {
        wc[c] = w[c * OUT_DIM + o];
        wsq = fmaf(wc[c], wc[c], wsq);
    }
#pragma unroll
    for (int c = 0; c < C_DIM; ++c)
        asm volatile("" : "+v"(wc[c]));   // forbid rematerialization into the loop
    const float bo = bias[o];
    const float base = -LOG2E * wsq;      // fold -log2e*||w||^2

    __syncthreads();

    const float* xl = xtile + rowGrp * ROWS_PER_WAVE * C_DIM;
    float* orow = out + (block_row0 + rowGrp * ROWS_PER_WAVE) * OUT_DIM + o;

    for (int r = 0; r < ROWS_PER_WAVE; ++r) {
        // Uniform-address ds_read_b128 x8: broadcast to all lanes, conflict-free.
        const float4* xr = reinterpret_cast<const float4*>(xl + r * C_DIM);
        float4 xv[8];
#pragma unroll
        for (int k = 0; k < 8; ++k) xv[k] = xr[k];

        float d0 = 0.f, d1 = 0.f, d2 = 0.f, d3 = 0.f;
#pragma unroll
        for (int k = 0; k < 8; k += 4) {
            d0 = fmaf(xv[k+0].x, wc[4*(k+0)+0], d0);
            d0 = fmaf(xv[k+0].y, wc[4*(k+0)+1], d0);
            d0 = fmaf(xv[k+0].z, wc[4*(k+0)+2], d0);
            d0 = fmaf(xv[k+0].w, wc[4*(k+0)+3], d0);
            d1 = fmaf(xv[k+1].x, wc[4*(k+1)+0], d1);
            d1 = fmaf(xv[k+1].y, wc[4*(k+1)+1], d1);
            d1 = fmaf(xv[k+1].z, wc[4*(k+1)+2], d1);
            d1 = fmaf(xv[k+1].w, wc[4*(k+1)+3], d1);
            d2 = fmaf(xv[k+2].x, wc[4*(k+2)+0], d2);
            d2 = fmaf(xv[k+2].y, wc[4*(k+2)+1], d2);
            d2 = fmaf(xv[k+2].z, wc[4*(k+2)+2], d2);
            d2 = fmaf(xv[k+2].w, wc[4*(k+2)+3], d2);
            d3 = fmaf(xv[k+3].x, wc[4*(k+3)+0], d3);
            d3 = fmaf(xv[k+3].y, wc[4*(k+3)+1], d3);
            d3 = fmaf(xv[k+3].z, wc[4*(k+3)+2], d3);
            d3 = fmaf(xv[k+3].w, wc[4*(k+3)+3], d3);
        }
        const float d = (d0 + d1) + (d2 + d3);

        // broadcast row r's xsq from lane r (uniform index -> SGPR)
        const float sxsq = __int_as_float(
            __builtin_amdgcn_readlane(__float_as_int(xsq_l), r));
        const float a = fmaf(d, 2.f * LOG2E, fmaf(sxsq, -LOG2E, base));
        // 64 lanes store 64 consecutive floats: 256 B coalesced.
        orow[(long)r * OUT_DIM] = exp2f(a) + bo;
    }
}

extern "C" void kernel_launch(void* const* d_in, const int* in_sizes, int n_in,
                              void* d_out, int out_size, void* d_ws, size_t ws_size,
                              hipStream_t stream) {
    const float* x = (const float*)d_in[0];
    const float* w = (const float*)d_in[1];
    const float* b = (const float*)d_in[2];
    float* out = (float*)d_out;

    const int total_rows = in_sizes[0] / C_DIM;   // 262144
    const int nblocks = (total_rows + ROWS_PER_BLOCK - 1) / ROWS_PER_BLOCK;  // 2048

    gaussian_rbf_kernel<<<nblocks, 256, 0, stream>>>(x, w, b, out, total_rows);
}